// Round 1
// baseline (2784.572 us; speedup 1.0000x reference)
//
#include <hip/hip_runtime.h>
#include <hip/hip_bf16.h>
#include <math.h>

#define SEQ 8192
#define NSYM 1000000
#define EPSC 1e-6f

// A buffer: SEQ rows of 80 gate pre-activations, padded for deep prefetch
#define A_ROWS 8200

__device__ __forceinline__ float rcp_(float x){ return __builtin_amdgcn_rcpf(x); }
__device__ __forceinline__ float sigf(float x){ return rcp_(1.f + __expf(-x)); }
__device__ __forceinline__ float tanhf_(float x){
  float ax = fabsf(x);
  float e  = __expf(2.f*ax);
  float t  = 1.f - 2.f*rcp_(e + 1.f);
  return copysignf(t, x);
}
__device__ __forceinline__ float softplusf_(float x){
  return fmaxf(x, 0.f) + log1pf(__expf(-fabsf(x)));
}
__device__ __forceinline__ float rdlane(float v, int lane){
  return __builtin_bit_cast(float, __builtin_amdgcn_readlane(__builtin_bit_cast(int, v), lane));
}

// ---------------- Kernel 1: time-parallel gate pre-activations ----------------
// A[t][j] = bih[j] + bhh[j] + sum_k emb[x[t]][k]*mask * Wih[j][k]
__global__ __launch_bounds__(320) void k_pre(const int* __restrict__ x,
    const float* __restrict__ emb, const float* __restrict__ Wih,
    const float* __restrict__ bih, const float* __restrict__ bhh,
    float* __restrict__ A){
  __shared__ float wih_s[80*21];      // +1 pad -> stride 21 (coprime with 32 banks)
  __shared__ float xe_s[4][20];
  int tid = threadIdx.x;
  for (int i = tid; i < 1600; i += 320)
    wih_s[(i/20)*21 + (i%20)] = Wih[i];
  if (tid < 80){
    int tl = tid/20, k = tid%20;
    int t  = blockIdx.x*4 + tl;
    int sym = x[t];
    xe_s[tl][k] = (sym == NSYM) ? 0.f : emb[(size_t)sym*20 + k];
  }
  __syncthreads();
  int tl = tid/80, j = tid%80;
  int t  = blockIdx.x*4 + tl;
  float acc = bih[j] + bhh[j];
  #pragma unroll
  for (int k=0;k<20;k++) acc = fmaf(xe_s[tl][k], wih_s[j*21+k], acc);
  A[(size_t)t*80 + j] = acc;
}

// ---------------- Kernel 2: sequential LSTM scan + DNC step + first MLP layer ----------------
__global__ __launch_bounds__(64) void k_seq(
    const float* __restrict__ A,
    const float* __restrict__ Whh,
    const float* __restrict__ ctrl_Wih, const float* __restrict__ ctrl_bih, const float* __restrict__ ctrl_bhh,
    const float* __restrict__ w_alloc_W, const float* __restrict__ w_alloc_b,
    const float* __restrict__ w_gate_W,  const float* __restrict__ w_gate_b,
    const float* __restrict__ w_erase_W, const float* __restrict__ w_erase_b,
    const float* __restrict__ w_add_W,   const float* __restrict__ w_add_b,
    const float* __restrict__ r_key_W,   const float* __restrict__ r_key_b,
    const float* __restrict__ r_beta_W,  const float* __restrict__ r_beta_b,
    const float* __restrict__ r_mode_W,  const float* __restrict__ r_mode_b,
    const float* __restrict__ out_W,     const float* __restrict__ out_b,
    const float* __restrict__ lin_W,     const float* __restrict__ lin_b,
    float* __restrict__ x5_out){
  const int u  = threadIdx.x;
  const int jj = (u < 20) ? u : 0;      // lanes >=20 shadow lane 0 (results unused)

  // recurrent weights in registers: rows j, 20+j, 40+j, 60+j of Whh[80][20]
  float wi[20], wf[20], wg[20], wo[20];
  #pragma unroll
  for (int k=0;k<20;k++){
    wi[k] = Whh[(0 +jj)*20+k];
    wf[k] = Whh[(20+jj)*20+k];
    wg[k] = Whh[(40+jj)*20+k];
    wo[k] = Whh[(60+jj)*20+k];
  }

  float h=0.f, c=0.f, s=0.f;

  auto step = [&](float& qi, float& qf, float& qg, float& qo, int tn){
    float ai=qi, af=qf, ag=qg, ao=qo;
    const float* p = A + (size_t)tn*80;        // prefetch 4 steps ahead
    qi = p[jj]; qf = p[20+jj]; qg = p[40+jj]; qo = p[60+jj];
    #pragma unroll
    for (int k=0;k<20;k++){
      float hk = rdlane(h, k);                 // sgpr broadcast of h[k]
      ai = fmaf(hk, wi[k], ai);
      af = fmaf(hk, wf[k], af);
      ag = fmaf(hk, wg[k], ag);
      ao = fmaf(hk, wo[k], ao);
    }
    c = fmaf(sigf(af), c, sigf(ai)*tanhf_(ag));
    h = sigf(ao)*tanhf_(c);
    s += h;
  };

  float q0i,q0f,q0g,q0o, q1i,q1f,q1g,q1o, q2i,q2f,q2g,q2o, q3i,q3f,q3g,q3o;
  { const float* p = A + 0*80;  q0i=p[jj]; q0f=p[20+jj]; q0g=p[40+jj]; q0o=p[60+jj]; }
  { const float* p = A + 1*80;  q1i=p[jj]; q1f=p[20+jj]; q1g=p[40+jj]; q1o=p[60+jj]; }
  { const float* p = A + 2*80;  q2i=p[jj]; q2f=p[20+jj]; q2g=p[40+jj]; q2o=p[60+jj]; }
  { const float* p = A + 3*80;  q3i=p[jj]; q3f=p[20+jj]; q3g=p[40+jj]; q3o=p[60+jj]; }

  for (int t=0; t<SEQ; t+=4){
    step(q0i,q0f,q0g,q0o, t+4);
    step(q1i,q1f,q1g,q1o, t+5);
    step(q2i,q2f,q2g,q2o, t+6);
    step(q3i,q3f,q3g,q3o, t+7);
  }

  // ---------------- DNC single step from zero state ----------------
  __shared__ float x4_s[20], h_s[64], rkey_s[64], rbeta_s[4], rknorm_s[4];
  __shared__ float erase_s[16], add_s[16], mode_s[12], wlw_s[16];
  __shared__ float mem_s[256], mnorm_s[16], wlr_s[64], rv_s[64], x4b_s[20];
  __shared__ float scal_s[2];

  if (u < 20) x4_s[u] = s;
  __syncthreads();

  // controller LSTMCell: input = cat(x4, zeros(64)); h0=c0=0
  // g split: i=[0,64) f=[64,128) g=[128,192) o=[192,256); sig(f)*c0 == 0
  {
    float gi = ctrl_bih[u]      + ctrl_bhh[u];
    float gG = ctrl_bih[128+u]  + ctrl_bhh[128+u];
    float go = ctrl_bih[192+u]  + ctrl_bhh[192+u];
    #pragma unroll
    for (int k=0;k<20;k++){
      float xk = x4_s[k];
      gi = fmaf(xk, ctrl_Wih[(0  +u)*84+k], gi);
      gG = fmaf(xk, ctrl_Wih[(128+u)*84+k], gG);
      go = fmaf(xk, ctrl_Wih[(192+u)*84+k], go);
    }
    float cc = sigf(gi)*tanhf_(gG);
    float hh = sigf(go)*tanhf_(cc);
    hh = fminf(fmaxf(hh, -20.f), 20.f);
    h_s[u] = hh;
  }
  __syncthreads();

  // head linears over h (64-wide dots). Dead at zero state: w_key, w_beta, r_free.
  {
    float d = r_key_b[u];
    #pragma unroll
    for (int k=0;k<64;k++) d = fmaf(h_s[k], r_key_W[u*64+k], d);
    rkey_s[u] = tanhf_(d);
  }
  if (u < 4){
    float d = r_beta_b[u];
    #pragma unroll
    for (int k=0;k<64;k++) d = fmaf(h_s[k], r_beta_W[u*64+k], d);
    rbeta_s[u] = softplusf_(d);
  }
  if (u >= 16 && u < 32){
    int e = u-16; float d = w_erase_b[e];
    #pragma unroll
    for (int k=0;k<64;k++) d = fmaf(h_s[k], w_erase_W[e*64+k], d);
    erase_s[e] = sigf(d);
  }
  if (u >= 32 && u < 48){
    int a = u-32; float d = w_add_b[a];
    #pragma unroll
    for (int k=0;k<64;k++) d = fmaf(h_s[k], w_add_W[a*64+k], d);
    add_s[a] = tanhf_(d);
  }
  if (u >= 48 && u < 60){
    int m = u-48; float d = r_mode_b[m];
    #pragma unroll
    for (int k=0;k<64;k++) d = fmaf(h_s[k], r_mode_W[m*64+k], d);
    mode_s[m] = d;
  }
  if (u == 60){
    float d = w_alloc_b[0];
    #pragma unroll
    for (int k=0;k<64;k++) d = fmaf(h_s[k], w_alloc_W[k], d);
    scal_s[0] = sigf(d);
  }
  if (u == 61){
    float d = w_gate_b[0];
    #pragma unroll
    for (int k=0;k<64;k++) d = fmaf(h_s[k], w_gate_W[k], d);
    scal_s[1] = sigf(d);
  }
  __syncthreads();

  const float alloc_gate = scal_s[0], write_gate = scal_s[1];

  // usage==0 exactly -> alloc[i] = (1-eps)*eps^i (stable top_k => identity perm);
  // write content weights = softmax(const) = 1/16 exactly.
  if (u < 16){
    float cp = 1.f;
    for (int i2=0;i2<u;i2++) cp *= EPSC;
    float alloc = (1.f-EPSC)*cp;
    wlw_s[u] = write_gate*(alloc_gate*alloc + (1.f-alloc_gate)*0.0625f);
  }
  if (u < 4){
    float s2 = 0.f;
    #pragma unroll
    for (int w=0;w<16;w++) s2 = fmaf(rkey_s[u*16+w], rkey_s[u*16+w], s2);
    rknorm_s[u] = sqrtf(s2) + EPSC;
  }
  __syncthreads();

  // mem = 1e-6*(1 - wlw x erase) + wlw x add
  for (int idx=u; idx<256; idx+=64){
    int n = idx>>4, w = idx&15;
    float wlw = wlw_s[n];
    mem_s[idx] = 1e-6f*(1.f - wlw*erase_s[w]) + wlw*add_s[w];
  }
  __syncthreads();
  if (u < 16){
    float s2 = 0.f;
    #pragma unroll
    for (int w=0;w<16;w++) s2 = fmaf(mem_s[u*16+w], mem_s[u*16+w], s2);
    mnorm_s[u] = sqrtf(s2) + EPSC;
  }
  __syncthreads();

  // read content weights + mode blend (fw=bw=0 since link==0, wl_r_prev==0)
  {
    int r = u>>4, n = u&15;
    float dot = 0.f;
    #pragma unroll
    for (int w=0;w<16;w++) dot = fmaf(rkey_s[r*16+w], mem_s[n*16+w], dot);
    float score = rbeta_s[r]*dot/(rknorm_s[r]*mnorm_s[n]);
    float mx = score;
    #pragma unroll
    for (int m2=1;m2<16;m2<<=1) mx = fmaxf(mx, __shfl_xor(mx, m2, 64));
    float p  = __expf(score - mx);
    float ps = p;
    #pragma unroll
    for (int m2=1;m2<16;m2<<=1) ps += __shfl_xor(ps, m2, 64);
    float wcr = p/ps;
    float m0 = mode_s[r*3+0], m1 = mode_s[r*3+1], m22 = mode_s[r*3+2];
    float mm = fmaxf(m0, fmaxf(m1, m22));
    float e0 = __expf(m0-mm), e1 = __expf(m1-mm), e2 = __expf(m22-mm);
    wlr_s[u] = (e2/(e0+e1+e2))*wcr;
  }
  __syncthreads();

  // read vectors
  {
    int r = u>>4, w = u&15;
    float rv = 0.f;
    #pragma unroll
    for (int n2=0;n2<16;n2++) rv = fmaf(wlr_s[r*16+n2], mem_s[n2*16+w], rv);
    rv_s[u] = rv;
  }
  __syncthreads();

  // x4b = out(cat(h, read_vec)); x5 = relu(lin(cat(x4, x4b)))
  if (u < 20){
    float a = out_b[u];
    #pragma unroll
    for (int k=0;k<64;k++) a = fmaf(h_s[k],  out_W[u*128+k],    a);
    #pragma unroll
    for (int k=0;k<64;k++) a = fmaf(rv_s[k], out_W[u*128+64+k], a);
    x4b_s[u] = a;
  }
  __syncthreads();
  if (u < 20){
    float a = lin_b[u];
    #pragma unroll
    for (int k=0;k<20;k++) a = fmaf(x4_s[k],  lin_W[u*40+k],    a);
    #pragma unroll
    for (int k=0;k<20;k++) a = fmaf(x4b_s[k], lin_W[u*40+20+k], a);
    x5_out[u] = fmaxf(a, 0.f);
  }
}

// ---------------- Kernel 3: final action layer ----------------
__global__ __launch_bounds__(256) void k_act(const float* __restrict__ x5,
    const float* __restrict__ actW, const float* __restrict__ actb,
    float* __restrict__ out){
  int a = blockIdx.x*256 + threadIdx.x;
  if (a < 1000){
    float acc = actb[a];
    #pragma unroll
    for (int j=0;j<20;j++) acc = fmaf(x5[j], actW[a*20+j], acc);
    out[a] = acc;
  }
}

extern "C" void kernel_launch(void* const* d_in, const int* in_sizes, int n_in,
                              void* d_out, int out_size, void* d_ws, size_t ws_size,
                              hipStream_t stream) {
  const int*   x         = (const int*)  d_in[0];
  const float* emb       = (const float*)d_in[1];
  const float* lstm_Wih  = (const float*)d_in[2];
  const float* lstm_Whh  = (const float*)d_in[3];
  const float* lstm_bih  = (const float*)d_in[4];
  const float* lstm_bhh  = (const float*)d_in[5];
  const float* ctrl_Wih  = (const float*)d_in[6];
  const float* ctrl_bih  = (const float*)d_in[8];
  const float* ctrl_bhh  = (const float*)d_in[9];
  const float* w_alloc_W = (const float*)d_in[14];
  const float* w_alloc_b = (const float*)d_in[15];
  const float* w_gate_W  = (const float*)d_in[16];
  const float* w_gate_b  = (const float*)d_in[17];
  const float* w_erase_W = (const float*)d_in[18];
  const float* w_erase_b = (const float*)d_in[19];
  const float* w_add_W   = (const float*)d_in[20];
  const float* w_add_b   = (const float*)d_in[21];
  const float* r_key_W   = (const float*)d_in[22];
  const float* r_key_b   = (const float*)d_in[23];
  const float* r_beta_W  = (const float*)d_in[24];
  const float* r_beta_b  = (const float*)d_in[25];
  const float* r_mode_W  = (const float*)d_in[28];
  const float* r_mode_b  = (const float*)d_in[29];
  const float* out_W     = (const float*)d_in[30];
  const float* out_b     = (const float*)d_in[31];
  const float* lin_W     = (const float*)d_in[32];
  const float* lin_b     = (const float*)d_in[33];
  const float* act_W     = (const float*)d_in[34];
  const float* act_b     = (const float*)d_in[35];

  float* A  = (float*)d_ws;                 // A_ROWS*80 floats (pad rows read-only garbage, unused)
  float* x5 = A + (size_t)A_ROWS*80;        // 20 floats

  k_pre<<<SEQ/4, 320, 0, stream>>>(x, emb, lstm_Wih, lstm_bih, lstm_bhh, A);
  k_seq<<<1, 64, 0, stream>>>(A, lstm_Whh,
      ctrl_Wih, ctrl_bih, ctrl_bhh,
      w_alloc_W, w_alloc_b, w_gate_W, w_gate_b,
      w_erase_W, w_erase_b, w_add_W, w_add_b,
      r_key_W, r_key_b, r_beta_W, r_beta_b,
      r_mode_W, r_mode_b, out_W, out_b, lin_W, lin_b, x5);
  k_act<<<4, 256, 0, stream>>>(x5, act_W, act_b, (float*)d_out);
}

// Round 3
// 1671.386 us; speedup vs baseline: 1.6660x; 1.6660x over previous
//
#include <hip/hip_runtime.h>
#include <hip/hip_bf16.h>
#include <math.h>

#define SEQ 8192
#define NSYM 1000000
#define EPSC 1e-6f

#define NGRP (SEQ/4)        // 2048 groups of 4 steps
#define NGRP_PAD 2052       // pad for prefetch overrun (reads up to group 2048)

__device__ __forceinline__ float rcp_(float x){ return __builtin_amdgcn_rcpf(x); }
__device__ __forceinline__ float exp2f_(float x){ return __builtin_amdgcn_exp2f(x); }
__device__ __forceinline__ float sigf(float x){ return rcp_(1.f + exp2f_(-1.44269504f*x)); }
__device__ __forceinline__ float tanhf_(float x){
  float e = exp2f_(2.88539008f*fabsf(x));
  float t = 1.f - 2.f*rcp_(e + 1.f);
  return copysignf(t, x);
}
__device__ __forceinline__ float softplusf_(float x){
  return fmaxf(x, 0.f) + log1pf(__expf(-fabsf(x)));
}
__device__ __forceinline__ float rdlane(float v, int lane){
  return __builtin_bit_cast(float, __builtin_amdgcn_readlane(__builtin_bit_cast(int, v), lane));
}
// exchange value with lane^32 partner — ds_bpermute-backed shfl (proven path)
__device__ __forceinline__ float xchg32(float v){
  return __shfl_xor(v, 32, 64);
}

// ---------------- Kernel 1: time-parallel gate pre-activations (packed layout) ----------------
// A2 float4 layout: [group][gaterow] -> float4 of 4 consecutive steps
__global__ __launch_bounds__(320) void k_pre(const int* __restrict__ x,
    const float* __restrict__ emb, const float* __restrict__ Wih,
    const float* __restrict__ bih, const float* __restrict__ bhh,
    float* __restrict__ A2){
  __shared__ float wih_s[80*21];      // +1 pad
  __shared__ float xe_s[4][20];
  int tid = threadIdx.x;
  for (int i = tid; i < 1600; i += 320)
    wih_s[(i/20)*21 + (i%20)] = Wih[i];
  if (tid < 80){
    int tl = tid/20, k = tid%20;
    int t  = blockIdx.x*4 + tl;
    int sym = x[t];
    xe_s[tl][k] = (sym == NSYM) ? 0.f : emb[(size_t)sym*20 + k];
  }
  __syncthreads();
  int tl = tid/80, j = tid%80;      // tl = t&3 within this group
  float acc = bih[j] + bhh[j];
  #pragma unroll
  for (int k=0;k<20;k++) acc = fmaf(xe_s[tl][k], wih_s[j*21+k], acc);
  A2[((size_t)blockIdx.x*80 + j)*4 + tl] = acc;
}

// ---------------- Kernel 2: sequential LSTM scan + DNC step + first MLP layer ----------------
__global__ __launch_bounds__(64) void k_seq(
    const float* __restrict__ A2,
    const float* __restrict__ Whh,
    const float* __restrict__ ctrl_Wih, const float* __restrict__ ctrl_bih, const float* __restrict__ ctrl_bhh,
    const float* __restrict__ w_alloc_W, const float* __restrict__ w_alloc_b,
    const float* __restrict__ w_gate_W,  const float* __restrict__ w_gate_b,
    const float* __restrict__ w_erase_W, const float* __restrict__ w_erase_b,
    const float* __restrict__ w_add_W,   const float* __restrict__ w_add_b,
    const float* __restrict__ r_key_W,   const float* __restrict__ r_key_b,
    const float* __restrict__ r_beta_W,  const float* __restrict__ r_beta_b,
    const float* __restrict__ r_mode_W,  const float* __restrict__ r_mode_b,
    const float* __restrict__ out_W,     const float* __restrict__ out_b,
    const float* __restrict__ lin_W,     const float* __restrict__ lin_b,
    float* __restrict__ x5_out){
  const int u    = threadIdx.x;
  const int half = u >> 5;                 // 0: computes (i,g) rows; 1: computes (f,o) rows, owns c/h
  const int j    = u & 31;
  const int jj   = (j < 20) ? j : 0;       // shadow lanes duplicate unit 0

  const int rowA = half ? (20+jj) : jj;        // f : i
  const int rowB = half ? (60+jj) : (40+jj);   // o : g

  // recurrent weight rows in registers
  float wA[20], wB[20];
  #pragma unroll
  for (int k=0;k<20;k++){ wA[k] = Whh[rowA*20+k]; wB[k] = Whh[rowB*20+k]; }

  float h=0.f, c=0.f, s=0.f;

  // one LSTM step; pa = this lane's gateA preactivation, pb = gateB preactivation
  auto stepf = [&](float pa, float pb){
    float a0 = pa, a1 = pb, b0 = 0.f, b1 = 0.f;   // 2x10 split accumulator chains
    #pragma unroll
    for (int k=0;k<10;k++){
      float hk  = rdlane(h, 32+k);      // h[k]   lives in lane 32+k
      float hk2 = rdlane(h, 42+k);      // h[10+k]
      a0 = fmaf(hk,  wA[k],    a0);
      a1 = fmaf(hk,  wB[k],    a1);
      b0 = fmaf(hk2, wA[10+k], b0);
      b1 = fmaf(hk2, wB[10+k], b1);
    }
    float acc0 = a0 + b0, acc1 = a1 + b1;
    float s0 = sigf(acc0);              // halfA: sig(i)   halfB: sig(f)
    float t1 = tanhf_(acc1);            // halfA: tanh(g)  halfB: (unused)
    float s1 = sigf(acc1);              // halfA: (unused) halfB: sig(o)
    float send = s0 * t1;               // halfA payload: sig(i)*tanh(g)
    float recv = xchg32(send);          // halfB receives it
    c = fmaf(s0, c, recv);              // halfB: c = sig(f)*c + sig(i)*tanh(g)
    h = s1 * tanhf_(c);                 // halfB: h = sig(o)*tanh(c)
    s += h;                             // halfB: sum of hidden states
  };

  const float4* A4 = (const float4*)A2;     // [group*80 + row]
  #define LD(g, r) A4[(size_t)(g)*80 + (r)]
  #define STEP4(va, vb) { stepf((va).x,(vb).x); stepf((va).y,(vb).y); stepf((va).z,(vb).z); stepf((va).w,(vb).w); }

  float4 a0v = LD(0,rowA), b0v = LD(0,rowB);
  float4 a1v = LD(1,rowA), b1v = LD(1,rowB);
  float4 a2v = LD(2,rowA), b2v = LD(2,rowB);

  for (int m=0; m<NGRP-2; m+=3){            // processes groups 0..2045
    STEP4(a0v,b0v); a0v = LD(m+3,rowA); b0v = LD(m+3,rowB);
    STEP4(a1v,b1v); a1v = LD(m+4,rowA); b1v = LD(m+4,rowB);
    STEP4(a2v,b2v); a2v = LD(m+5,rowA); b2v = LD(m+5,rowB);
  }
  STEP4(a0v,b0v);                           // group 2046
  STEP4(a1v,b1v);                           // group 2047
  #undef LD
  #undef STEP4

  // ---------------- DNC single step from zero state ----------------
  __shared__ float x4_s[20], h_s[64], rkey_s[64], rbeta_s[4], rknorm_s[4];
  __shared__ float erase_s[16], add_s[16], mode_s[12], wlw_s[16];
  __shared__ float mem_s[256], mnorm_s[16], wlr_s[64], rv_s[64], x4b_s[20];
  __shared__ float scal_s[2];

  if (u >= 32 && u < 52) x4_s[u-32] = s;    // s lives in upper-half lanes
  __syncthreads();

  // controller LSTMCell: input = cat(x4, zeros(64)); h0=c0=0
  {
    float gi = ctrl_bih[u]      + ctrl_bhh[u];
    float gG = ctrl_bih[128+u]  + ctrl_bhh[128+u];
    float go = ctrl_bih[192+u]  + ctrl_bhh[192+u];
    #pragma unroll
    for (int k=0;k<20;k++){
      float xk = x4_s[k];
      gi = fmaf(xk, ctrl_Wih[(0  +u)*84+k], gi);
      gG = fmaf(xk, ctrl_Wih[(128+u)*84+k], gG);
      go = fmaf(xk, ctrl_Wih[(192+u)*84+k], go);
    }
    float cc = sigf(gi)*tanhf_(gG);
    float hh = sigf(go)*tanhf_(cc);
    hh = fminf(fmaxf(hh, -20.f), 20.f);
    h_s[u] = hh;
  }
  __syncthreads();

  // head linears over h (dead at zero state: w_key, w_beta, r_free)
  {
    float d = r_key_b[u];
    #pragma unroll
    for (int k=0;k<64;k++) d = fmaf(h_s[k], r_key_W[u*64+k], d);
    rkey_s[u] = tanhf_(d);
  }
  if (u < 4){
    float d = r_beta_b[u];
    #pragma unroll
    for (int k=0;k<64;k++) d = fmaf(h_s[k], r_beta_W[u*64+k], d);
    rbeta_s[u] = softplusf_(d);
  }
  if (u >= 16 && u < 32){
    int e = u-16; float d = w_erase_b[e];
    #pragma unroll
    for (int k=0;k<64;k++) d = fmaf(h_s[k], w_erase_W[e*64+k], d);
    erase_s[e] = sigf(d);
  }
  if (u >= 32 && u < 48){
    int a = u-32; float d = w_add_b[a];
    #pragma unroll
    for (int k=0;k<64;k++) d = fmaf(h_s[k], w_add_W[a*64+k], d);
    add_s[a] = tanhf_(d);
  }
  if (u >= 48 && u < 60){
    int m = u-48; float d = r_mode_b[m];
    #pragma unroll
    for (int k=0;k<64;k++) d = fmaf(h_s[k], r_mode_W[m*64+k], d);
    mode_s[m] = d;
  }
  if (u == 60){
    float d = w_alloc_b[0];
    #pragma unroll
    for (int k=0;k<64;k++) d = fmaf(h_s[k], w_alloc_W[k], d);
    scal_s[0] = sigf(d);
  }
  if (u == 61){
    float d = w_gate_b[0];
    #pragma unroll
    for (int k=0;k<64;k++) d = fmaf(h_s[k], w_gate_W[k], d);
    scal_s[1] = sigf(d);
  }
  __syncthreads();

  const float alloc_gate = scal_s[0], write_gate = scal_s[1];

  // usage==0 -> alloc[i]=(1-eps)*eps^i (stable top_k, identity perm); content = 1/16 exactly
  if (u < 16){
    float cp = 1.f;
    for (int i2=0;i2<u;i2++) cp *= EPSC;
    float alloc = (1.f-EPSC)*cp;
    wlw_s[u] = write_gate*(alloc_gate*alloc + (1.f-alloc_gate)*0.0625f);
  }
  if (u < 4){
    float s2 = 0.f;
    #pragma unroll
    for (int w=0;w<16;w++) s2 = fmaf(rkey_s[u*16+w], rkey_s[u*16+w], s2);
    rknorm_s[u] = sqrtf(s2) + EPSC;
  }
  __syncthreads();

  for (int idx=u; idx<256; idx+=64){
    int n = idx>>4, w = idx&15;
    float wlw = wlw_s[n];
    mem_s[idx] = 1e-6f*(1.f - wlw*erase_s[w]) + wlw*add_s[w];
  }
  __syncthreads();
  if (u < 16){
    float s2 = 0.f;
    #pragma unroll
    for (int w=0;w<16;w++) s2 = fmaf(mem_s[u*16+w], mem_s[u*16+w], s2);
    mnorm_s[u] = sqrtf(s2) + EPSC;
  }
  __syncthreads();

  // read content weights + mode blend (fw=bw=0 since link==0, wl_r_prev==0)
  {
    int r = u>>4, n = u&15;
    float dot = 0.f;
    #pragma unroll
    for (int w=0;w<16;w++) dot = fmaf(rkey_s[r*16+w], mem_s[n*16+w], dot);
    float score = rbeta_s[r]*dot/(rknorm_s[r]*mnorm_s[n]);
    float mx = score;
    #pragma unroll
    for (int m2=1;m2<16;m2<<=1) mx = fmaxf(mx, __shfl_xor(mx, m2, 64));
    float p  = __expf(score - mx);
    float ps = p;
    #pragma unroll
    for (int m2=1;m2<16;m2<<=1) ps += __shfl_xor(ps, m2, 64);
    float wcr = p/ps;
    float m0 = mode_s[r*3+0], m1 = mode_s[r*3+1], m22 = mode_s[r*3+2];
    float mm = fmaxf(m0, fmaxf(m1, m22));
    float e0 = __expf(m0-mm), e1 = __expf(m1-mm), e2 = __expf(m22-mm);
    wlr_s[u] = (e2/(e0+e1+e2))*wcr;
  }
  __syncthreads();

  {
    int r = u>>4, w = u&15;
    float rv = 0.f;
    #pragma unroll
    for (int n2=0;n2<16;n2++) rv = fmaf(wlr_s[r*16+n2], mem_s[n2*16+w], rv);
    rv_s[u] = rv;
  }
  __syncthreads();

  if (u < 20){
    float a = out_b[u];
    #pragma unroll
    for (int k=0;k<64;k++) a = fmaf(h_s[k],  out_W[u*128+k],    a);
    #pragma unroll
    for (int k=0;k<64;k++) a = fmaf(rv_s[k], out_W[u*128+64+k], a);
    x4b_s[u] = a;
  }
  __syncthreads();
  if (u < 20){
    float a = lin_b[u];
    #pragma unroll
    for (int k=0;k<20;k++) a = fmaf(x4_s[k],  lin_W[u*40+k],    a);
    #pragma unroll
    for (int k=0;k<20;k++) a = fmaf(x4b_s[k], lin_W[u*40+20+k], a);
    x5_out[u] = fmaxf(a, 0.f);
  }
}

// ---------------- Kernel 3: final action layer ----------------
__global__ __launch_bounds__(256) void k_act(const float* __restrict__ x5,
    const float* __restrict__ actW, const float* __restrict__ actb,
    float* __restrict__ out){
  int a = blockIdx.x*256 + threadIdx.x;
  if (a < 1000){
    float acc = actb[a];
    #pragma unroll
    for (int j=0;j<20;j++) acc = fmaf(x5[j], actW[a*20+j], acc);
    out[a] = acc;
  }
}

extern "C" void kernel_launch(void* const* d_in, const int* in_sizes, int n_in,
                              void* d_out, int out_size, void* d_ws, size_t ws_size,
                              hipStream_t stream) {
  const int*   x         = (const int*)  d_in[0];
  const float* emb       = (const float*)d_in[1];
  const float* lstm_Wih  = (const float*)d_in[2];
  const float* lstm_Whh  = (const float*)d_in[3];
  const float* lstm_bih  = (const float*)d_in[4];
  const float* lstm_bhh  = (const float*)d_in[5];
  const float* ctrl_Wih  = (const float*)d_in[6];
  const float* ctrl_bih  = (const float*)d_in[8];
  const float* ctrl_bhh  = (const float*)d_in[9];
  const float* w_alloc_W = (const float*)d_in[14];
  const float* w_alloc_b = (const float*)d_in[15];
  const float* w_gate_W  = (const float*)d_in[16];
  const float* w_gate_b  = (const float*)d_in[17];
  const float* w_erase_W = (const float*)d_in[18];
  const float* w_erase_b = (const float*)d_in[19];
  const float* w_add_W   = (const float*)d_in[20];
  const float* w_add_b   = (const float*)d_in[21];
  const float* r_key_W   = (const float*)d_in[22];
  const float* r_key_b   = (const float*)d_in[23];
  const float* r_beta_W  = (const float*)d_in[24];
  const float* r_beta_b  = (const float*)d_in[25];
  const float* r_mode_W  = (const float*)d_in[28];
  const float* r_mode_b  = (const float*)d_in[29];
  const float* out_W     = (const float*)d_in[30];
  const float* out_b     = (const float*)d_in[31];
  const float* lin_W     = (const float*)d_in[32];
  const float* lin_b     = (const float*)d_in[33];
  const float* act_W     = (const float*)d_in[34];
  const float* act_b     = (const float*)d_in[35];

  float* A2 = (float*)d_ws;                       // NGRP_PAD*320 floats
  float* x5 = A2 + (size_t)NGRP_PAD*320;          // 20 floats

  k_pre<<<NGRP, 320, 0, stream>>>(x, emb, lstm_Wih, lstm_bih, lstm_bhh, A2);
  k_seq<<<1, 64, 0, stream>>>(A2, lstm_Whh,
      ctrl_Wih, ctrl_bih, ctrl_bhh,
      w_alloc_W, w_alloc_b, w_gate_W, w_gate_b,
      w_erase_W, w_erase_b, w_add_W, w_add_b,
      r_key_W, r_key_b, r_beta_W, r_beta_b,
      r_mode_W, r_mode_b, out_W, out_b, lin_W, lin_b, x5);
  k_act<<<4, 256, 0, stream>>>(x5, act_W, act_b, (float*)d_out);
}

// Round 7
// 1629.241 us; speedup vs baseline: 1.7091x; 1.0259x over previous
//
#include <hip/hip_runtime.h>
#include <hip/hip_bf16.h>
#include <math.h>

#define SEQ 8192
#define NSYM 1000000
#define EPSC 1e-6f

#define NGRP (SEQ/4)        // 2048 groups of 4 steps
#define NGRP_PAD 2052       // pad for prefetch overrun

typedef float v2f __attribute__((ext_vector_type(2)));

__device__ __forceinline__ float rcp_(float x){ return __builtin_amdgcn_rcpf(x); }
__device__ __forceinline__ float exp2f_(float x){ return __builtin_amdgcn_exp2f(x); }
__device__ __forceinline__ float sigf(float x){ return rcp_(1.f + exp2f_(-1.44269504f*x)); }
__device__ __forceinline__ float tanhf_(float x){
  float e = exp2f_(2.88539008f*fabsf(x));
  float t = 1.f - 2.f*rcp_(e + 1.f);
  return copysignf(t, x);
}
__device__ __forceinline__ float softplusf_(float x){
  return fmaxf(x, 0.f) + log1pf(__expf(-fabsf(x)));
}
__device__ __forceinline__ float rdlane(float v, int lane){
  return __builtin_bit_cast(float, __builtin_amdgcn_readlane(__builtin_bit_cast(int, v), lane));
}
// exchange with lane^32 partner — ds_bpermute-backed shfl (PROVEN in R2;
// v_permlane32_swap failed with both builtin and asm formulations)
__device__ __forceinline__ float xchg32(float v){
  return __shfl_xor(v, 32, 64);
}

// ---------------- Kernel 1: time-parallel gate pre-activations (packed layout) ----------------
__global__ __launch_bounds__(320) void k_pre(const int* __restrict__ x,
    const float* __restrict__ emb, const float* __restrict__ Wih,
    const float* __restrict__ bih, const float* __restrict__ bhh,
    float* __restrict__ A2){
  __shared__ float wih_s[80*21];      // +1 pad
  __shared__ float xe_s[4][20];
  int tid = threadIdx.x;
  for (int i = tid; i < 1600; i += 320)
    wih_s[(i/20)*21 + (i%20)] = Wih[i];
  if (tid < 80){
    int tl = tid/20, k = tid%20;
    int t  = blockIdx.x*4 + tl;
    int sym = x[t];
    xe_s[tl][k] = (sym == NSYM) ? 0.f : emb[(size_t)sym*20 + k];
  }
  __syncthreads();
  int tl = tid/80, j = tid%80;      // tl = t&3 within this group
  float acc = bih[j] + bhh[j];
  #pragma unroll
  for (int k=0;k<20;k++) acc = fmaf(xe_s[tl][k], wih_s[j*21+k], acc);
  A2[((size_t)blockIdx.x*80 + j)*4 + tl] = acc;
}

// ---------------- Kernel 2: sequential LSTM scan + DNC step + first MLP layer ----------------
__global__ __launch_bounds__(64) void k_seq(
    const float* __restrict__ A2,
    const float* __restrict__ Whh,
    const float* __restrict__ ctrl_Wih, const float* __restrict__ ctrl_bih, const float* __restrict__ ctrl_bhh,
    const float* __restrict__ w_alloc_W, const float* __restrict__ w_alloc_b,
    const float* __restrict__ w_gate_W,  const float* __restrict__ w_gate_b,
    const float* __restrict__ w_erase_W, const float* __restrict__ w_erase_b,
    const float* __restrict__ w_add_W,   const float* __restrict__ w_add_b,
    const float* __restrict__ r_key_W,   const float* __restrict__ r_key_b,
    const float* __restrict__ r_beta_W,  const float* __restrict__ r_beta_b,
    const float* __restrict__ r_mode_W,  const float* __restrict__ r_mode_b,
    const float* __restrict__ out_W,     const float* __restrict__ out_b,
    const float* __restrict__ lin_W,     const float* __restrict__ lin_b,
    float* __restrict__ x5_out){
  const int u    = threadIdx.x;
  const int half = u >> 5;                 // 0: computes (i,g) rows; 1: computes (f,o) rows, owns c/h
  const int j    = u & 31;
  const int jj   = (j < 20) ? j : 0;       // shadow lanes duplicate unit 0

  const int rowA = half ? (20+jj) : jj;        // f : i
  const int rowB = half ? (60+jj) : (40+jj);   // o : g

  // paired recurrent weights: W{q}[k] = {WhhA[kq], WhhB[kq]} for 4 k-quarters
  v2f W0[5], W1[5], W2[5], W3[5];
  #pragma unroll
  for (int k=0;k<5;k++){
    W0[k] = (v2f){Whh[rowA*20+k   ], Whh[rowB*20+k   ]};
    W1[k] = (v2f){Whh[rowA*20+5+k ], Whh[rowB*20+5+k ]};
    W2[k] = (v2f){Whh[rowA*20+10+k], Whh[rowB*20+10+k]};
    W3[k] = (v2f){Whh[rowA*20+15+k], Whh[rowB*20+15+k]};
  }

  // merged-nonlinearity constant: halfA computes tanh via e^{2|x|}, halfB sigmoid via e^{-x}
  const float mtr = half ? -1.44269504f : 2.88539008f;

  float h=0.f, c=0.f, s=0.f;

  auto stepf = [&](float pa, float pb){
    v2f A0 = (v2f){pa, pb}, A1 = (v2f){0.f,0.f}, A2v = (v2f){0.f,0.f}, A3 = (v2f){0.f,0.f};
    #pragma unroll
    for (int k=0;k<5;k++){
      float h0 = rdlane(h, 32+k);
      float h1 = rdlane(h, 37+k);
      float h2 = rdlane(h, 42+k);
      float h3 = rdlane(h, 47+k);
      A0  = __builtin_elementwise_fma((v2f){h0,h0}, W0[k], A0);
      A1  = __builtin_elementwise_fma((v2f){h1,h1}, W1[k], A1);
      A2v = __builtin_elementwise_fma((v2f){h2,h2}, W2[k], A2v);
      A3  = __builtin_elementwise_fma((v2f){h3,h3}, W3[k], A3);
    }
    v2f S = (A0+A1) + (A2v+A3);
    float s0 = sigf(S.x);               // halfA: sig(i)   halfB: sig(f)
    float xx = half ? S.y : fabsf(S.y);
    float e  = exp2f_(mtr*xx);          // halfA: e^{2|g|}  halfB: e^{-o}
    float z  = rcp_(1.f + e);
    float u2 = half ? z                                  // sig(o)
                    : copysignf(fmaf(-2.f, z, 1.f), S.y); // tanh(g)
    float send = s0 * u2;               // halfA payload: sig(i)*tanh(g)
    float recv = xchg32(send);
    c = fmaf(s0, c, recv);              // halfB: c = sig(f)*c + sig(i)*tanh(g)
    h = u2 * tanhf_(c);                 // halfB: h = sig(o)*tanh(c)
    s += h;
  };

  const float4* A4 = (const float4*)A2;     // [group*80 + row]
  #define LD(g, r) A4[(size_t)(g)*80 + (r)]
  #define STEP4(va, vb) { stepf((va).x,(vb).x); stepf((va).y,(vb).y); stepf((va).z,(vb).z); stepf((va).w,(vb).w); }

  float4 a0v = LD(0,rowA), b0v = LD(0,rowB);
  float4 a1v = LD(1,rowA), b1v = LD(1,rowB);
  float4 a2v = LD(2,rowA), b2v = LD(2,rowB);

  for (int m=0; m<NGRP-2; m+=3){            // groups 0..2045
    STEP4(a0v,b0v); a0v = LD(m+3,rowA); b0v = LD(m+3,rowB);
    STEP4(a1v,b1v); a1v = LD(m+4,rowA); b1v = LD(m+4,rowB);
    STEP4(a2v,b2v); a2v = LD(m+5,rowA); b2v = LD(m+5,rowB);
  }
  STEP4(a0v,b0v);                           // group 2046
  STEP4(a1v,b1v);                           // group 2047
  #undef LD
  #undef STEP4

  // ---------------- DNC single step from zero state ----------------
  __shared__ float x4_s[20], h_s[64], rkey_s[64], rbeta_s[4], rknorm_s[4];
  __shared__ float erase_s[16], add_s[16], mode_s[12], wlw_s[16];
  __shared__ float mem_s[256], mnorm_s[16], wlr_s[64], rv_s[64], x4b_s[20];
  __shared__ float scal_s[2];

  if (u >= 32 && u < 52) x4_s[u-32] = s;    // s lives in upper-half lanes
  __syncthreads();

  // controller LSTMCell: input = cat(x4, zeros(64)); h0=c0=0
  {
    float gi = ctrl_bih[u]      + ctrl_bhh[u];
    float gG = ctrl_bih[128+u]  + ctrl_bhh[128+u];
    float go = ctrl_bih[192+u]  + ctrl_bhh[192+u];
    #pragma unroll
    for (int k=0;k<20;k++){
      float xk = x4_s[k];
      gi = fmaf(xk, ctrl_Wih[(0  +u)*84+k], gi);
      gG = fmaf(xk, ctrl_Wih[(128+u)*84+k], gG);
      go = fmaf(xk, ctrl_Wih[(192+u)*84+k], go);
    }
    float cc = sigf(gi)*tanhf_(gG);
    float hh = sigf(go)*tanhf_(cc);
    hh = fminf(fmaxf(hh, -20.f), 20.f);
    h_s[u] = hh;
  }
  __syncthreads();

  // head linears over h (dead at zero state: w_key, w_beta, r_free)
  {
    float d = r_key_b[u];
    #pragma unroll
    for (int k=0;k<64;k++) d = fmaf(h_s[k], r_key_W[u*64+k], d);
    rkey_s[u] = tanhf_(d);
  }
  if (u < 4){
    float d = r_beta_b[u];
    #pragma unroll
    for (int k=0;k<64;k++) d = fmaf(h_s[k], r_beta_W[u*64+k], d);
    rbeta_s[u] = softplusf_(d);
  }
  if (u >= 16 && u < 32){
    int e = u-16; float d = w_erase_b[e];
    #pragma unroll
    for (int k=0;k<64;k++) d = fmaf(h_s[k], w_erase_W[e*64+k], d);
    erase_s[e] = sigf(d);
  }
  if (u >= 32 && u < 48){
    int a = u-32; float d = w_add_b[a];
    #pragma unroll
    for (int k=0;k<64;k++) d = fmaf(h_s[k], w_add_W[a*64+k], d);
    add_s[a] = tanhf_(d);
  }
  if (u >= 48 && u < 60){
    int m = u-48; float d = r_mode_b[m];
    #pragma unroll
    for (int k=0;k<64;k++) d = fmaf(h_s[k], r_mode_W[m*64+k], d);
    mode_s[m] = d;
  }
  if (u == 60){
    float d = w_alloc_b[0];
    #pragma unroll
    for (int k=0;k<64;k++) d = fmaf(h_s[k], w_alloc_W[k], d);
    scal_s[0] = sigf(d);
  }
  if (u == 61){
    float d = w_gate_b[0];
    #pragma unroll
    for (int k=0;k<64;k++) d = fmaf(h_s[k], w_gate_W[k], d);
    scal_s[1] = sigf(d);
  }
  __syncthreads();

  const float alloc_gate = scal_s[0], write_gate = scal_s[1];

  // usage==0 -> alloc[i]=(1-eps)*eps^i (stable top_k, identity perm); content = 1/16 exactly
  if (u < 16){
    float cp = 1.f;
    for (int i2=0;i2<u;i2++) cp *= EPSC;
    float alloc = (1.f-EPSC)*cp;
    wlw_s[u] = write_gate*(alloc_gate*alloc + (1.f-alloc_gate)*0.0625f);
  }
  if (u < 4){
    float s2 = 0.f;
    #pragma unroll
    for (int w=0;w<16;w++) s2 = fmaf(rkey_s[u*16+w], rkey_s[u*16+w], s2);
    rknorm_s[u] = sqrtf(s2) + EPSC;
  }
  __syncthreads();

  for (int idx=u; idx<256; idx+=64){
    int n = idx>>4, w = idx&15;
    float wlw = wlw_s[n];
    mem_s[idx] = 1e-6f*(1.f - wlw*erase_s[w]) + wlw*add_s[w];
  }
  __syncthreads();
  if (u < 16){
    float s2 = 0.f;
    #pragma unroll
    for (int w=0;w<16;w++) s2 = fmaf(mem_s[u*16+w], mem_s[u*16+w], s2);
    mnorm_s[u] = sqrtf(s2) + EPSC;
  }
  __syncthreads();

  // read content weights + mode blend (fw=bw=0 since link==0, wl_r_prev==0)
  {
    int r = u>>4, n = u&15;
    float dot = 0.f;
    #pragma unroll
    for (int w=0;w<16;w++) dot = fmaf(rkey_s[r*16+w], mem_s[n*16+w], dot);
    float score = rbeta_s[r]*dot/(rknorm_s[r]*mnorm_s[n]);
    float mx = score;
    #pragma unroll
    for (int m2=1;m2<16;m2<<=1) mx = fmaxf(mx, __shfl_xor(mx, m2, 64));
    float p  = __expf(score - mx);
    float ps = p;
    #pragma unroll
    for (int m2=1;m2<16;m2<<=1) ps += __shfl_xor(ps, m2, 64);
    float wcr = p/ps;
    float m0 = mode_s[r*3+0], m1 = mode_s[r*3+1], m22 = mode_s[r*3+2];
    float mm = fmaxf(m0, fmaxf(m1, m22));
    float e0 = __expf(m0-mm), e1 = __expf(m1-mm), e2 = __expf(m22-mm);
    wlr_s[u] = (e2/(e0+e1+e2))*wcr;
  }
  __syncthreads();

  {
    int r = u>>4, w = u&15;
    float rv = 0.f;
    #pragma unroll
    for (int n2=0;n2<16;n2++) rv = fmaf(wlr_s[r*16+n2], mem_s[n2*16+w], rv);
    rv_s[u] = rv;
  }
  __syncthreads();

  if (u < 20){
    float a = out_b[u];
    #pragma unroll
    for (int k=0;k<64;k++) a = fmaf(h_s[k],  out_W[u*128+k],    a);
    #pragma unroll
    for (int k=0;k<64;k++) a = fmaf(rv_s[k], out_W[u*128+64+k], a);
    x4b_s[u] = a;
  }
  __syncthreads();
  if (u < 20){
    float a = lin_b[u];
    #pragma unroll
    for (int k=0;k<20;k++) a = fmaf(x4_s[k],  lin_W[u*40+k],    a);
    #pragma unroll
    for (int k=0;k<20;k++) a = fmaf(x4b_s[k], lin_W[u*40+20+k], a);
    x5_out[u] = fmaxf(a, 0.f);
  }
}

// ---------------- Kernel 3: final action layer ----------------
__global__ __launch_bounds__(256) void k_act(const float* __restrict__ x5,
    const float* __restrict__ actW, const float* __restrict__ actb,
    float* __restrict__ out){
  int a = blockIdx.x*256 + threadIdx.x;
  if (a < 1000){
    float acc = actb[a];
    #pragma unroll
    for (int j=0;j<20;j++) acc = fmaf(x5[j], actW[a*20+j], acc);
    out[a] = acc;
  }
}

extern "C" void kernel_launch(void* const* d_in, const int* in_sizes, int n_in,
                              void* d_out, int out_size, void* d_ws, size_t ws_size,
                              hipStream_t stream) {
  const int*   x         = (const int*)  d_in[0];
  const float* emb       = (const float*)d_in[1];
  const float* lstm_Wih  = (const float*)d_in[2];
  const float* lstm_Whh  = (const float*)d_in[3];
  const float* lstm_bih  = (const float*)d_in[4];
  const float* lstm_bhh  = (const float*)d_in[5];
  const float* ctrl_Wih  = (const float*)d_in[6];
  const float* ctrl_bih  = (const float*)d_in[8];
  const float* ctrl_bhh  = (const float*)d_in[9];
  const float* w_alloc_W = (const float*)d_in[14];
  const float* w_alloc_b = (const float*)d_in[15];
  const float* w_gate_W  = (const float*)d_in[16];
  const float* w_gate_b  = (const float*)d_in[17];
  const float* w_erase_W = (const float*)d_in[18];
  const float* w_erase_b = (const float*)d_in[19];
  const float* w_add_W   = (const float*)d_in[20];
  const float* w_add_b   = (const float*)d_in[21];
  const float* r_key_W   = (const float*)d_in[22];
  const float* r_key_b   = (const float*)d_in[23];
  const float* r_beta_W  = (const float*)d_in[24];
  const float* r_beta_b  = (const float*)d_in[25];
  const float* r_mode_W  = (const float*)d_in[28];
  const float* r_mode_b  = (const float*)d_in[29];
  const float* out_W     = (const float*)d_in[30];
  const float* out_b     = (const float*)d_in[31];
  const float* lin_W     = (const float*)d_in[32];
  const float* lin_b     = (const float*)d_in[33];
  const float* act_W     = (const float*)d_in[34];
  const float* act_b     = (const float*)d_in[35];

  float* A2 = (float*)d_ws;                       // NGRP_PAD*320 floats
  float* x5 = A2 + (size_t)NGRP_PAD*320;          // 20 floats

  k_pre<<<NGRP, 320, 0, stream>>>(x, emb, lstm_Wih, lstm_bih, lstm_bhh, A2);
  k_seq<<<1, 64, 0, stream>>>(A2, lstm_Whh,
      ctrl_Wih, ctrl_bih, ctrl_bhh,
      w_alloc_W, w_alloc_b, w_gate_W, w_gate_b,
      w_erase_W, w_erase_b, w_add_W, w_add_b,
      r_key_W, r_key_b, r_beta_W, r_beta_b,
      r_mode_W, r_mode_b, out_W, out_b, lin_W, lin_b, x5);
  k_act<<<4, 256, 0, stream>>>(x5, act_W, act_b, (float*)d_out);
}